// Round 1
// baseline (758.187 us; speedup 1.0000x reference)
//
#include <hip/hip_runtime.h>
#include <stdint.h>

// ---- problem constants ----
#define NTOK 32768
#define EMB  1024
#define QKVN 3072   // 3*EMB
#define NH   16
#define HD   64

typedef __bf16 bf16x8 __attribute__((ext_vector_type(8)));
typedef float  floatx4 __attribute__((ext_vector_type(4)));
typedef unsigned int   uintx4  __attribute__((ext_vector_type(4)));
typedef unsigned short ushortx4 __attribute__((ext_vector_type(4)));

__device__ __forceinline__ float bf_lo(unsigned int w){
    unsigned int x = w << 16; float f; __builtin_memcpy(&f, &x, 4); return f;
}
__device__ __forceinline__ float bf_hi(unsigned int w){
    unsigned int x = w & 0xffff0000u; float f; __builtin_memcpy(&f, &x, 4); return f;
}
__device__ __forceinline__ unsigned short f2bf_rne(float f){
    unsigned int x; __builtin_memcpy(&x, &f, 4);
    x += 0x7fffu + ((x >> 16) & 1u);
    return (unsigned short)(x >> 16);
}

__device__ __forceinline__ void async_copy16(void* lds, const void* gsrc){
    __builtin_amdgcn_global_load_lds(
        (const __attribute__((address_space(1))) unsigned int*)gsrc,
        (__attribute__((address_space(3))) unsigned int*)lds,
        16, 0, 0);
}

// ---------------- cast fp32 -> bf16, vectorized x4 ----------------
__global__ __launch_bounds__(256) void cast_f32_bf16(const float* __restrict__ in,
                                                     unsigned short* __restrict__ out,
                                                     int n4){
    int idx = blockIdx.x * 256 + threadIdx.x;
    if (idx < n4){
        floatx4 v = ((const floatx4*)in)[idx];
        ushortx4 o;
        o[0] = f2bf_rne(v[0]); o[1] = f2bf_rne(v[1]);
        o[2] = f2bf_rne(v[2]); o[3] = f2bf_rne(v[3]);
        ((ushortx4*)out)[idx] = o;
    }
}

// ---------------- QKV GEMM: C[m][n] = sum_k A[m][k]*B[n][k] + bias[n] ----------------
// A = h_bf16 [32768][1024], B = W_bf16 [3072][1024], C = qkv fp32 [32768][3072]
// m97 structure: 128x128 tile, BK=32, 256 threads (4 waves, 2x2 of 64x64),
// global_load_lds width=16, mfma_f32_16x16x32_bf16.
__global__ __launch_bounds__(256) void qkv_gemm(const unsigned short* __restrict__ A,
                                                const unsigned short* __restrict__ B,
                                                const float* __restrict__ bias,
                                                float* __restrict__ C){
    __shared__ unsigned short As[128 * 32];   // 8 KB, K-major, no pad (global_load_lds needs linear)
    __shared__ unsigned short Bs[128 * 32];   // 8 KB

    const int tid  = threadIdx.x;
    const int m0   = blockIdx.y * 128;
    const int n0   = blockIdx.x * 128;
    const int lane = tid & 63;
    const int wave = tid >> 6;
    const int wm   = (wave >> 1) * 64;
    const int wn   = (wave & 1) * 64;
    const int r16  = lane & 15;   // MFMA row/col-in-16
    const int quad = lane >> 4;   // 0..3

    floatx4 acc[4][4];
    #pragma unroll
    for (int mi = 0; mi < 4; mi++)
        #pragma unroll
        for (int ni = 0; ni < 4; ni++)
            acc[mi][ni] = floatx4{0.f, 0.f, 0.f, 0.f};

    for (int kt = 0; kt < EMB; kt += 32){
        // stage 128x32 bf16 A-tile and B-tile: 512 chunks of 16B each, 2 per thread
        #pragma unroll
        for (int s = 0; s < 2; s++){
            int c   = tid + s * 256;
            int row = c >> 2;
            int k8  = (c & 3) * 8;
            async_copy16(&As[c * 8], &A[(size_t)(m0 + row) * EMB + kt + k8]);
            async_copy16(&Bs[c * 8], &B[(size_t)(n0 + row) * EMB + kt + k8]);
        }
        __syncthreads();

        bf16x8 af[4], bb[4];
        #pragma unroll
        for (int mi = 0; mi < 4; mi++)
            af[mi] = *(const bf16x8*)&As[(wm + mi * 16 + r16) * 32 + quad * 8];
        #pragma unroll
        for (int ni = 0; ni < 4; ni++)
            bb[ni] = *(const bf16x8*)&Bs[(wn + ni * 16 + r16) * 32 + quad * 8];
        #pragma unroll
        for (int mi = 0; mi < 4; mi++)
            #pragma unroll
            for (int ni = 0; ni < 4; ni++)
                acc[mi][ni] = __builtin_amdgcn_mfma_f32_16x16x32_bf16(
                                  af[mi], bb[ni], acc[mi][ni], 0, 0, 0);
        __syncthreads();
    }

    // epilogue: C/D layout col = lane&15, row = quad*4 + r  (m89/m91-verified)
    #pragma unroll
    for (int ni = 0; ni < 4; ni++){
        int gcol = n0 + wn + ni * 16 + r16;
        float bv = bias[gcol];
        #pragma unroll
        for (int mi = 0; mi < 4; mi++){
            #pragma unroll
            for (int r = 0; r < 4; r++){
                int grow = m0 + wm + mi * 16 + quad * 4 + r;
                C[(size_t)grow * QKVN + gcol] = acc[mi][ni][r] + bv;
            }
        }
    }
}

// ---------------- per-token 16-head cross-head attention ----------------
// 8 tokens/block, 128 threads, thread = (token t = tid>>4, head i = tid&15).
// k staged bf16 (LDS), v staged fp32 (LDS), q read fp32 from global.
// out_flat[i*NTOK*64 + n*64 + d] = sum_j softmax_j(q[i]·k[j]/32) * v[j][d]
#define AT_TOK 8
#define KS_STRIDE 1032   // 1024 + 8 shorts: token base moves 4 banks
#define VS_STRIDE 1028   // 1024 + 4 floats: token base moves 4 banks

__global__ __launch_bounds__(128) void attn_kernel(const float* __restrict__ qkv,
                                                   float* __restrict__ out){
    __shared__ unsigned short ks[AT_TOK * KS_STRIDE]; // 16.1 KB
    __shared__ float          vs[AT_TOK * VS_STRIDE]; // 32.9 KB

    const int tid = threadIdx.x;
    const int n0  = blockIdx.x * AT_TOK;

    // stage k+v region: qkv[n][1024..3071], 8 tokens x 2048 floats = 4096 float4
    #pragma unroll
    for (int it = 0; it < 32; it++){
        int f  = tid + it * 128;
        int tt = f >> 9;              // 512 float4 per token
        int e  = (f & 511) * 4;       // element 0..2044 within k|v region
        floatx4 val = *(const floatx4*)&qkv[(size_t)(n0 + tt) * QKVN + EMB + e];
        if (e < 1024){                // k part -> bf16
            ushortx4 o;
            o[0] = f2bf_rne(val[0]); o[1] = f2bf_rne(val[1]);
            o[2] = f2bf_rne(val[2]); o[3] = f2bf_rne(val[3]);
            *(ushortx4*)&ks[tt * KS_STRIDE + e] = o;
        } else {                      // v part -> fp32
            *(floatx4*)&vs[tt * VS_STRIDE + (e - 1024)] = val;
        }
    }
    __syncthreads();

    const int t = tid >> 4;
    const int i = tid & 15;
    const int n = n0 + t;

    // q row fp32 into registers
    float qf[64];
    {
        const floatx4* qp = (const floatx4*)(qkv + (size_t)n * QKVN + i * HD);
        #pragma unroll
        for (int d4 = 0; d4 < 16; d4++){
            floatx4 v = qp[d4];
            qf[d4*4+0] = v[0]; qf[d4*4+1] = v[1]; qf[d4*4+2] = v[2]; qf[d4*4+3] = v[3];
        }
    }

    // scores s[j] = (q[i] . k[j]) / 32
    float s[16];
    #pragma unroll
    for (int j = 0; j < 16; j++){
        const uintx4* kr = (const uintx4*)&ks[t * KS_STRIDE + j * HD];
        float acc = 0.f;
        #pragma unroll
        for (int d8 = 0; d8 < 8; d8++){
            uintx4 kk = kr[d8];
            acc += qf[d8*8+0] * bf_lo(kk[0]);
            acc += qf[d8*8+1] * bf_hi(kk[0]);
            acc += qf[d8*8+2] * bf_lo(kk[1]);
            acc += qf[d8*8+3] * bf_hi(kk[1]);
            acc += qf[d8*8+4] * bf_lo(kk[2]);
            acc += qf[d8*8+5] * bf_hi(kk[2]);
            acc += qf[d8*8+6] * bf_lo(kk[3]);
            acc += qf[d8*8+7] * bf_hi(kk[3]);
        }
        s[j] = acc * 0.03125f;
    }

    // softmax over j
    float m = s[0];
    #pragma unroll
    for (int j = 1; j < 16; j++) m = fmaxf(m, s[j]);
    float p[16], l = 0.f;
    #pragma unroll
    for (int j = 0; j < 16; j++){ p[j] = __expf(s[j] - m); l += p[j]; }
    float inv = 1.f / l;

    // out[i][d] = sum_j p[j]*v[j][d]
    float o[64];
    #pragma unroll
    for (int d = 0; d < 64; d++) o[d] = 0.f;
    #pragma unroll
    for (int j = 0; j < 16; j++){
        float pj = p[j] * inv;
        const floatx4* vr = (const floatx4*)&vs[t * VS_STRIDE + j * HD];
        #pragma unroll
        for (int d4 = 0; d4 < 16; d4++){
            floatx4 vv = vr[d4];
            o[d4*4+0] += pj * vv[0]; o[d4*4+1] += pj * vv[1];
            o[d4*4+2] += pj * vv[2]; o[d4*4+3] += pj * vv[3];
        }
    }

    // out_flat[i*NTOK*64 + n*64 + d]
    float* op = out + (size_t)i * (NTOK * HD) + (size_t)n * HD;
    #pragma unroll
    for (int d4 = 0; d4 < 16; d4++){
        floatx4 ov;
        ov[0] = o[d4*4+0]; ov[1] = o[d4*4+1]; ov[2] = o[d4*4+2]; ov[3] = o[d4*4+3];
        ((floatx4*)op)[d4] = ov;
    }
}

extern "C" void kernel_launch(void* const* d_in, const int* in_sizes, int n_in,
                              void* d_out, int out_size, void* d_ws, size_t ws_size,
                              hipStream_t stream){
    const float* h = (const float*)d_in[0];   // [32768][1024]
    const float* W = (const float*)d_in[1];   // [3072][1024]
    const float* b = (const float*)d_in[2];   // [3072]
    float* out = (float*)d_out;               // 33554432 fp32

    char* ws = (char*)d_ws;
    unsigned short* h_bf = (unsigned short*)ws;                           // 64 MB
    unsigned short* w_bf = (unsigned short*)(ws + (size_t)64 * 1024 * 1024); // 6 MB
    float* qkv = (float*)(ws + (size_t)72 * 1024 * 1024);                 // 384 MB

    // casts
    cast_f32_bf16<<<(NTOK * EMB / 4 + 255) / 256, 256, 0, stream>>>(h, h_bf, NTOK * EMB / 4);
    cast_f32_bf16<<<(QKVN * EMB / 4 + 255) / 256, 256, 0, stream>>>(W, w_bf, QKVN * EMB / 4);

    // qkv = h @ W^T + b
    dim3 ggrid(QKVN / 128, NTOK / 128);   // (24, 256)
    qkv_gemm<<<ggrid, 256, 0, stream>>>(h_bf, w_bf, b, qkv);

    // per-token cross-head attention
    attn_kernel<<<NTOK / AT_TOK, 128, 0, stream>>>(qkv, out);
}

// Round 2
// 547.436 us; speedup vs baseline: 1.3850x; 1.3850x over previous
//
#include <hip/hip_runtime.h>
#include <stdint.h>

// ---- problem constants ----
#define NTOK 32768
#define EMB  1024
#define QKVN 3072   // 3*EMB
#define NH   16
#define HD   64

typedef __bf16 bf16x8 __attribute__((ext_vector_type(8)));
typedef float  floatx4 __attribute__((ext_vector_type(4)));
typedef unsigned int   uintx4  __attribute__((ext_vector_type(4)));
typedef unsigned short ushortx4 __attribute__((ext_vector_type(4)));

__device__ __forceinline__ float bf_lo(unsigned int w){
    unsigned int x = w << 16; float f; __builtin_memcpy(&f, &x, 4); return f;
}
__device__ __forceinline__ float bf_hi(unsigned int w){
    unsigned int x = w & 0xffff0000u; float f; __builtin_memcpy(&f, &x, 4); return f;
}
__device__ __forceinline__ float bf2f(unsigned short s){
    unsigned int x = ((unsigned int)s) << 16; float f; __builtin_memcpy(&f, &x, 4); return f;
}
__device__ __forceinline__ unsigned short f2bf_rne(float f){
    unsigned int x; __builtin_memcpy(&x, &f, 4);
    x += 0x7fffu + ((x >> 16) & 1u);
    return (unsigned short)(x >> 16);
}

__device__ __forceinline__ void async_copy16(void* lds, const void* gsrc){
    __builtin_amdgcn_global_load_lds(
        (const __attribute__((address_space(1))) unsigned int*)gsrc,
        (__attribute__((address_space(3))) unsigned int*)lds,
        16, 0, 0);
}

// ---------------- cast fp32 -> bf16, vectorized x4 ----------------
__global__ __launch_bounds__(256) void cast_f32_bf16(const float* __restrict__ in,
                                                     unsigned short* __restrict__ out,
                                                     int n4){
    int idx = blockIdx.x * 256 + threadIdx.x;
    if (idx < n4){
        floatx4 v = ((const floatx4*)in)[idx];
        ushortx4 o;
        o[0] = f2bf_rne(v[0]); o[1] = f2bf_rne(v[1]);
        o[2] = f2bf_rne(v[2]); o[3] = f2bf_rne(v[3]);
        ((ushortx4*)out)[idx] = o;
    }
}

// ---------------- QKV GEMM: C[m][n] = sum_k A[m][k]*B[n][k] + bias[n], C bf16 ----------------
__global__ __launch_bounds__(256) void qkv_gemm(const unsigned short* __restrict__ A,
                                                const unsigned short* __restrict__ B,
                                                const float* __restrict__ bias,
                                                unsigned short* __restrict__ C){
    __shared__ unsigned short As[128 * 32];   // 8 KB, K-major, linear (global_load_lds)
    __shared__ unsigned short Bs[128 * 32];   // 8 KB

    const int tid  = threadIdx.x;
    const int m0   = blockIdx.y * 128;
    const int n0   = blockIdx.x * 128;
    const int lane = tid & 63;
    const int wave = tid >> 6;
    const int wm   = (wave >> 1) * 64;
    const int wn   = (wave & 1) * 64;
    const int r16  = lane & 15;
    const int quad = lane >> 4;

    floatx4 acc[4][4];
    #pragma unroll
    for (int mi = 0; mi < 4; mi++)
        #pragma unroll
        for (int ni = 0; ni < 4; ni++)
            acc[mi][ni] = floatx4{0.f, 0.f, 0.f, 0.f};

    for (int kt = 0; kt < EMB; kt += 32){
        #pragma unroll
        for (int s = 0; s < 2; s++){
            int c   = tid + s * 256;
            int row = c >> 2;
            int k8  = (c & 3) * 8;
            async_copy16(&As[c * 8], &A[(size_t)(m0 + row) * EMB + kt + k8]);
            async_copy16(&Bs[c * 8], &B[(size_t)(n0 + row) * EMB + kt + k8]);
        }
        __syncthreads();

        bf16x8 af[4], bb[4];
        #pragma unroll
        for (int mi = 0; mi < 4; mi++)
            af[mi] = *(const bf16x8*)&As[(wm + mi * 16 + r16) * 32 + quad * 8];
        #pragma unroll
        for (int ni = 0; ni < 4; ni++)
            bb[ni] = *(const bf16x8*)&Bs[(wn + ni * 16 + r16) * 32 + quad * 8];
        #pragma unroll
        for (int mi = 0; mi < 4; mi++)
            #pragma unroll
            for (int ni = 0; ni < 4; ni++)
                acc[mi][ni] = __builtin_amdgcn_mfma_f32_16x16x32_bf16(
                                  af[mi], bb[ni], acc[mi][ni], 0, 0, 0);
        __syncthreads();
    }

    // epilogue: C/D layout col = lane&15, row = quad*4 + r (verified)
    #pragma unroll
    for (int ni = 0; ni < 4; ni++){
        int gcol = n0 + wn + ni * 16 + r16;
        float bv = bias[gcol];
        #pragma unroll
        for (int mi = 0; mi < 4; mi++){
            #pragma unroll
            for (int r = 0; r < 4; r++){
                int grow = m0 + wm + mi * 16 + quad * 4 + r;
                C[(size_t)grow * QKVN + gcol] = f2bf_rne(acc[mi][ni][r] + bv);
            }
        }
    }
}

// ---------------- per-token 16-head cross-head attention (two-phase) ----------------
// 8 tokens/block, 128 threads.
// Stage k|v (bf16, 4096B/token) via global_load_lds, padded token stride.
// Phase A: thread=(t, head i): scores + softmax -> ps[t][j][i] (fp32, transposed)
// Phase B: thread=(t, d4): out[i][d4] for all 16 i; coalesced 256B stores per head.
#define AT_TOK 8
#define KV_STRIDE 2080    // shorts per token: 2048 + 32 pad (4160B; token base +16 banks)
#define PS_TSTRIDE 264    // floats per token: 256 + 8 pad

__global__ __launch_bounds__(128) void attn_kernel(const unsigned short* __restrict__ qkv,
                                                   float* __restrict__ out){
    __shared__ unsigned short kv[AT_TOK * KV_STRIDE]; // 33.3 KB: [t][ k(1024) | v(1024) ]
    __shared__ float          ps[AT_TOK * PS_TSTRIDE];// 8.4 KB:  [t][j][i]

    const int tid  = threadIdx.x;
    const int n0   = blockIdx.x * AT_TOK;
    const int wave = tid >> 6;
    const int lane = tid & 63;

    // ---- stage: each wave stages 4 tokens x 4 chunks of 1KB (lane-linear per chunk) ----
    #pragma unroll
    for (int r = 0; r < 16; r++){
        int t = wave * 4 + (r >> 2);
        int c = r & 3;                          // 1KB chunk within token (512 shorts)
        async_copy16(&kv[t * KV_STRIDE + c * 512 + lane * 8],
                     &qkv[(size_t)(n0 + t) * QKVN + EMB + c * 512 + lane * 8]);
    }
    __syncthreads();

    // ---- phase A: scores + softmax ----
    {
        const int t = tid >> 4;
        const int i = tid & 15;
        const int n = n0 + t;

        float qf[64];
        {
            const uintx4* qp = (const uintx4*)(qkv + (size_t)n * QKVN + i * HD);
            #pragma unroll
            for (int d8 = 0; d8 < 8; d8++){
                uintx4 q = qp[d8];
                qf[d8*8+0] = bf_lo(q[0]); qf[d8*8+1] = bf_hi(q[0]);
                qf[d8*8+2] = bf_lo(q[1]); qf[d8*8+3] = bf_hi(q[1]);
                qf[d8*8+4] = bf_lo(q[2]); qf[d8*8+5] = bf_hi(q[2]);
                qf[d8*8+6] = bf_lo(q[3]); qf[d8*8+7] = bf_hi(q[3]);
            }
        }

        float s[16];
        #pragma unroll
        for (int j = 0; j < 16; j++){
            const uintx4* kr = (const uintx4*)&kv[t * KV_STRIDE + j * HD];
            float acc = 0.f;
            #pragma unroll
            for (int d8 = 0; d8 < 8; d8++){
                uintx4 kk = kr[d8];
                acc += qf[d8*8+0] * bf_lo(kk[0]);
                acc += qf[d8*8+1] * bf_hi(kk[0]);
                acc += qf[d8*8+2] * bf_lo(kk[1]);
                acc += qf[d8*8+3] * bf_hi(kk[1]);
                acc += qf[d8*8+4] * bf_lo(kk[2]);
                acc += qf[d8*8+5] * bf_hi(kk[2]);
                acc += qf[d8*8+6] * bf_lo(kk[3]);
                acc += qf[d8*8+7] * bf_hi(kk[3]);
            }
            s[j] = acc * 0.03125f;
        }

        float m = s[0];
        #pragma unroll
        for (int j = 1; j < 16; j++) m = fmaxf(m, s[j]);
        float p[16], l = 0.f;
        #pragma unroll
        for (int j = 0; j < 16; j++){ p[j] = __expf(s[j] - m); l += p[j]; }
        float inv = 1.f / l;

        #pragma unroll
        for (int j = 0; j < 16; j++)
            ps[t * PS_TSTRIDE + j * 16 + i] = p[j] * inv;
    }
    __syncthreads();

    // ---- phase B: out[i][d] = sum_j p[i][j] * v[j][d] ----
    {
        const int t  = tid >> 4;
        const int d4 = tid & 15;
        const int n  = n0 + t;

        floatx4 o[16];
        #pragma unroll
        for (int i = 0; i < 16; i++) o[i] = floatx4{0.f, 0.f, 0.f, 0.f};

        #pragma unroll
        for (int j = 0; j < 16; j++){
            ushortx4 vv = *(const ushortx4*)&kv[t * KV_STRIDE + 1024 + j * HD + d4 * 4];
            float v0 = bf2f(vv[0]), v1 = bf2f(vv[1]), v2 = bf2f(vv[2]), v3 = bf2f(vv[3]);
            const floatx4* pj = (const floatx4*)&ps[t * PS_TSTRIDE + j * 16];
            #pragma unroll
            for (int g = 0; g < 4; g++){
                floatx4 pg = pj[g];
                #pragma unroll
                for (int e = 0; e < 4; e++){
                    float pv = pg[e];
                    int i = g * 4 + e;
                    o[i][0] += pv * v0; o[i][1] += pv * v1;
                    o[i][2] += pv * v2; o[i][3] += pv * v3;
                }
            }
        }

        #pragma unroll
        for (int i = 0; i < 16; i++){
            float* op = out + (size_t)i * (NTOK * HD) + (size_t)n * HD;
            ((floatx4*)op)[d4] = o[i];
        }
    }
}

extern "C" void kernel_launch(void* const* d_in, const int* in_sizes, int n_in,
                              void* d_out, int out_size, void* d_ws, size_t ws_size,
                              hipStream_t stream){
    const float* h = (const float*)d_in[0];   // [32768][1024]
    const float* W = (const float*)d_in[1];   // [3072][1024]
    const float* b = (const float*)d_in[2];   // [3072]
    float* out = (float*)d_out;               // 33554432 fp32

    char* ws = (char*)d_ws;
    unsigned short* h_bf = (unsigned short*)ws;                              // 64 MB
    unsigned short* w_bf = (unsigned short*)(ws + (size_t)64 * 1024 * 1024); // 6 MB
    unsigned short* qkv  = (unsigned short*)(ws + (size_t)72 * 1024 * 1024); // 192 MB bf16

    cast_f32_bf16<<<(NTOK * EMB / 4 + 255) / 256, 256, 0, stream>>>(h, h_bf, NTOK * EMB / 4);
    cast_f32_bf16<<<(QKVN * EMB / 4 + 255) / 256, 256, 0, stream>>>(W, w_bf, QKVN * EMB / 4);

    dim3 ggrid(QKVN / 128, NTOK / 128);   // (24, 256)
    qkv_gemm<<<ggrid, 256, 0, stream>>>(h_bf, w_bf, b, qkv);

    attn_kernel<<<NTOK / AT_TOK, 128, 0, stream>>>(qkv, out);
}

// Round 3
// 522.618 us; speedup vs baseline: 1.4507x; 1.0475x over previous
//
#include <hip/hip_runtime.h>
#include <stdint.h>

// ---- problem constants ----
#define NTOK 32768
#define EMB  1024
#define QKVN 3072   // 3*EMB
#define NH   16
#define HD   64

typedef __bf16 bf16x8 __attribute__((ext_vector_type(8)));
typedef float  floatx4 __attribute__((ext_vector_type(4)));
typedef unsigned int   uintx4   __attribute__((ext_vector_type(4)));
typedef unsigned short ushortx4 __attribute__((ext_vector_type(4)));
typedef unsigned short ushortx8 __attribute__((ext_vector_type(8)));

__device__ __forceinline__ unsigned short f2bf_rne(float f){
    unsigned int x; __builtin_memcpy(&x, &f, 4);
    x += 0x7fffu + ((x >> 16) & 1u);
    return (unsigned short)(x >> 16);
}

__device__ __forceinline__ void async_copy16(void* lds, const void* gsrc){
    __builtin_amdgcn_global_load_lds(
        (const __attribute__((address_space(1))) unsigned int*)gsrc,
        (__attribute__((address_space(3))) unsigned int*)lds,
        16, 0, 0);
}

// ---------------- cast fp32 -> bf16, vectorized x4 ----------------
__global__ __launch_bounds__(256) void cast_f32_bf16(const float* __restrict__ in,
                                                     unsigned short* __restrict__ out,
                                                     int n4){
    int idx = blockIdx.x * 256 + threadIdx.x;
    if (idx < n4){
        floatx4 v = ((const floatx4*)in)[idx];
        ushortx4 o;
        o[0] = f2bf_rne(v[0]); o[1] = f2bf_rne(v[1]);
        o[2] = f2bf_rne(v[2]); o[3] = f2bf_rne(v[3]);
        ((ushortx4*)out)[idx] = o;
    }
}

// ---------------- QKV GEMM: C[m][n] = sum_k A[m][k]*B[n][k] + bias[n], C bf16 ----------------
__global__ __launch_bounds__(256) void qkv_gemm(const unsigned short* __restrict__ A,
                                                const unsigned short* __restrict__ B,
                                                const float* __restrict__ bias,
                                                unsigned short* __restrict__ C){
    __shared__ unsigned short As[128 * 32];   // 8 KB, K-major, linear (global_load_lds)
    __shared__ unsigned short Bs[128 * 32];   // 8 KB

    const int tid  = threadIdx.x;
    const int m0   = blockIdx.y * 128;
    const int n0   = blockIdx.x * 128;
    const int lane = tid & 63;
    const int wave = tid >> 6;
    const int wm   = (wave >> 1) * 64;
    const int wn   = (wave & 1) * 64;
    const int r16  = lane & 15;
    const int quad = lane >> 4;

    floatx4 acc[4][4];
    #pragma unroll
    for (int mi = 0; mi < 4; mi++)
        #pragma unroll
        for (int ni = 0; ni < 4; ni++)
            acc[mi][ni] = floatx4{0.f, 0.f, 0.f, 0.f};

    for (int kt = 0; kt < EMB; kt += 32){
        #pragma unroll
        for (int s = 0; s < 2; s++){
            int c   = tid + s * 256;
            int row = c >> 2;
            int k8  = (c & 3) * 8;
            async_copy16(&As[c * 8], &A[(size_t)(m0 + row) * EMB + kt + k8]);
            async_copy16(&Bs[c * 8], &B[(size_t)(n0 + row) * EMB + kt + k8]);
        }
        __syncthreads();

        bf16x8 af[4], bb[4];
        #pragma unroll
        for (int mi = 0; mi < 4; mi++)
            af[mi] = *(const bf16x8*)&As[(wm + mi * 16 + r16) * 32 + quad * 8];
        #pragma unroll
        for (int ni = 0; ni < 4; ni++)
            bb[ni] = *(const bf16x8*)&Bs[(wn + ni * 16 + r16) * 32 + quad * 8];
        #pragma unroll
        for (int mi = 0; mi < 4; mi++)
            #pragma unroll
            for (int ni = 0; ni < 4; ni++)
                acc[mi][ni] = __builtin_amdgcn_mfma_f32_16x16x32_bf16(
                                  af[mi], bb[ni], acc[mi][ni], 0, 0, 0);
        __syncthreads();
    }

    // epilogue: C/D layout col = lane&15, row = quad*4 + r (verified)
    #pragma unroll
    for (int ni = 0; ni < 4; ni++){
        int gcol = n0 + wn + ni * 16 + r16;
        float bv = bias[gcol];
        #pragma unroll
        for (int mi = 0; mi < 4; mi++){
            #pragma unroll
            for (int r = 0; r < 4; r++){
                int grow = m0 + wm + mi * 16 + quad * 4 + r;
                C[(size_t)grow * QKVN + gcol] = f2bf_rne(acc[mi][ni][r] + bv);
            }
        }
    }
}

// ---------------- MFMA per-token cross-head attention ----------------
// 4 tokens/block, 256 threads, one wave per token.
// LDS per token (shorts): k[16][72] @0, vT[64][24] @1152, p_bf16[16][24] @2688 -> 3072
// S = Q·K^T via 2x mfma_16x16x32 (K=64); softmax in C-layout (shfl over j);
// P->LDS->A-frag; PV via 4x mfma_16x16x32 with K padded to 32 (quads 2,3 zero).
#define TOKL 3072
#define KOFF 0
#define VOFF 1152
#define POFF 2688

__global__ __launch_bounds__(256) void attn_mfma(const unsigned short* __restrict__ qkv,
                                                 float* __restrict__ out){
    __shared__ unsigned short sm[4 * TOKL];   // 24 KB

    const int tid = threadIdx.x;
    const int n0  = blockIdx.x * 4;

    // ---- stage K (row-padded) and V (transposed) ----
    // 512 chunks of 8 elems each for K, same for V; 2 of each per thread.
    #pragma unroll
    for (int s = 0; s < 2; s++){
        int c   = tid + s * 256;
        int t   = c >> 7;
        int rem = c & 127;
        int j   = rem >> 3;
        int d8  = (rem & 7) * 8;
        // K chunk: k[t][j][d8..d8+7] -> padded row
        ushortx8 kk = *(const ushortx8*)&qkv[(size_t)(n0 + t) * QKVN + EMB + j * HD + d8];
        *(ushortx8*)&sm[t * TOKL + KOFF + j * 72 + d8] = kk;
        // V chunk: v[t][j][d8..d8+7] -> vT[d][j] scalar scatter
        ushortx8 vv = *(const ushortx8*)&qkv[(size_t)(n0 + t) * QKVN + 2 * EMB + j * HD + d8];
        #pragma unroll
        for (int e = 0; e < 8; e++)
            sm[t * TOKL + VOFF + (d8 + e) * 24 + j] = vv[e];
    }
    __syncthreads();

    const int wave = tid >> 6;
    const int lane = tid & 63;
    const int col  = lane & 15;   // n-index of MFMA (j for S, d_local for O)
    const int quad = lane >> 4;
    const int n    = n0 + wave;
    unsigned short* tb = &sm[wave * TOKL];

    // ---- S = Q·K^T ----
    const unsigned short* qrow = qkv + (size_t)n * QKVN + col * HD;
    bf16x8 qf0 = *(const bf16x8*)(qrow + quad * 8);
    bf16x8 qf1 = *(const bf16x8*)(qrow + 32 + quad * 8);
    bf16x8 kf0 = *(const bf16x8*)&tb[KOFF + col * 72 + quad * 8];
    bf16x8 kf1 = *(const bf16x8*)&tb[KOFF + col * 72 + 32 + quad * 8];

    floatx4 sAcc = floatx4{0.f, 0.f, 0.f, 0.f};
    sAcc = __builtin_amdgcn_mfma_f32_16x16x32_bf16(qf0, kf0, sAcc, 0, 0, 0);
    sAcc = __builtin_amdgcn_mfma_f32_16x16x32_bf16(qf1, kf1, sAcc, 0, 0, 0);

    // ---- softmax over j (16 lanes of the quad-group hold j=0..15 for rows quad*4+r) ----
    #pragma unroll
    for (int r = 0; r < 4; r++){
        float sv = sAcc[r] * 0.03125f;
        float m = sv;
        m = fmaxf(m, __shfl_xor(m, 1));
        m = fmaxf(m, __shfl_xor(m, 2));
        m = fmaxf(m, __shfl_xor(m, 4));
        m = fmaxf(m, __shfl_xor(m, 8));
        float p = __expf(sv - m);
        float l = p;
        l += __shfl_xor(l, 1);
        l += __shfl_xor(l, 2);
        l += __shfl_xor(l, 4);
        l += __shfl_xor(l, 8);
        p *= 1.f / l;
        // p[i = quad*4+r][j = col]
        tb[POFF + (quad * 4 + r) * 24 + col] = f2bf_rne(p);
    }
    // wave-private LDS region: program-order ds_write -> ds_read, compiler inserts lgkmcnt

    // ---- P A-frag (K padded to 32; quads 2,3 supply zeros) ----
    bf16x8 pf;
    #pragma unroll
    for (int z = 0; z < 8; z++) pf[z] = (__bf16)0.0f;
    if (quad < 2) pf = *(const bf16x8*)&tb[POFF + col * 24 + quad * 8];

    // ---- O = P·V, 4 d-blocks of 16 ----
    #pragma unroll
    for (int dblk = 0; dblk < 4; dblk++){
        bf16x8 vf;
        #pragma unroll
        for (int z = 0; z < 8; z++) vf[z] = (__bf16)0.0f;
        if (quad < 2) vf = *(const bf16x8*)&tb[VOFF + (dblk * 16 + col) * 24 + quad * 8];
        floatx4 o = __builtin_amdgcn_mfma_f32_16x16x32_bf16(
                        pf, vf, floatx4{0.f, 0.f, 0.f, 0.f}, 0, 0, 0);
        // D layout: col = d_local, row = quad*4+r = head i
        #pragma unroll
        for (int r = 0; r < 4; r++){
            int i = quad * 4 + r;
            out[(size_t)i * (NTOK * HD) + (size_t)n * HD + dblk * 16 + col] = o[r];
        }
    }
}

extern "C" void kernel_launch(void* const* d_in, const int* in_sizes, int n_in,
                              void* d_out, int out_size, void* d_ws, size_t ws_size,
                              hipStream_t stream){
    const float* h = (const float*)d_in[0];   // [32768][1024]
    const float* W = (const float*)d_in[1];   // [3072][1024]
    const float* b = (const float*)d_in[2];   // [3072]
    float* out = (float*)d_out;               // 33554432 fp32

    char* ws = (char*)d_ws;
    unsigned short* h_bf = (unsigned short*)ws;                              // 64 MB
    unsigned short* w_bf = (unsigned short*)(ws + (size_t)64 * 1024 * 1024); // 6 MB
    unsigned short* qkv  = (unsigned short*)(ws + (size_t)72 * 1024 * 1024); // 192 MB bf16

    cast_f32_bf16<<<(NTOK * EMB / 4 + 255) / 256, 256, 0, stream>>>(h, h_bf, NTOK * EMB / 4);
    cast_f32_bf16<<<(QKVN * EMB / 4 + 255) / 256, 256, 0, stream>>>(W, w_bf, QKVN * EMB / 4);

    dim3 ggrid(QKVN / 128, NTOK / 128);   // (24, 256)
    qkv_gemm<<<ggrid, 256, 0, stream>>>(h_bf, w_bf, b, qkv);

    attn_mfma<<<NTOK / 4, 256, 0, stream>>>(qkv, out);
}